// Round 16
// baseline (115.755 us; speedup 1.0000x reference)
//
#include <hip/hip_runtime.h>
#include <hip/hip_bf16.h>
#include <math.h>

#define BB 4
#define NN 4096
#define CC 384
#define NHH 6
#define HDD 64
#define NKK 1024
#define LN_EPS 1e-5f

typedef _Float16 half8 __attribute__((ext_vector_type(8)));
typedef _Float16 half4v __attribute__((ext_vector_type(4)));
typedef _Float16 half2v __attribute__((ext_vector_type(2)));
typedef float f32x4 __attribute__((ext_vector_type(4)));

#define MFMA16(a, b, c) __builtin_amdgcn_mfma_f32_16x16x32_f16((a), (b), (c), 0, 0, 0)

#define GLL16(src, dst)                                                       \
    __builtin_amdgcn_global_load_lds(                                         \
        (const __attribute__((address_space(1))) void*)(src),                 \
        (__attribute__((address_space(3))) void*)(dst), 16, 0, 0)

// ---------------------------------------------------------------------------
// Q projection: A = x (f32, split on stage), W = pre-split pair,
// Y = (x @ Wq^T + bq) * 0.125 as f16 hi/lo pair. 768 blocks = 3/CU.
// ---------------------------------------------------------------------------
__global__ __launch_bounds__(256) void gemm_q(
    const float* __restrict__ x,
    const _Float16* __restrict__ Whi, const _Float16* __restrict__ Wlo,
    const float* __restrict__ bias,
    _Float16* __restrict__ Yhi, _Float16* __restrict__ Ylo)
{
    __shared__ _Float16 AhiS[128 * 64];
    __shared__ _Float16 AloS[128 * 64];
    __shared__ _Float16 WhiS[64 * 64];
    __shared__ _Float16 WloS[64 * 64];

    const int tid = threadIdx.x;
    const int bm = blockIdx.x * 128;
    const int bn = blockIdx.y * 64;
    const int w = tid >> 6, lane = tid & 63;
    const int g = lane >> 4, n15 = lane & 15;

    f32x4 zero4 = {0.f, 0.f, 0.f, 0.f};
    f32x4 acc_hi[2][4], acc_lo[2][4];
#pragma unroll
    for (int mf = 0; mf < 2; ++mf)
#pragma unroll
        for (int nt = 0; nt < 4; ++nt) { acc_hi[mf][nt] = zero4; acc_lo[mf][nt] = zero4; }

    for (int k0 = 0; k0 < CC; k0 += 64) {
        __syncthreads();
#pragma unroll
        for (int i = 0; i < 8; ++i) {
            int id = tid + 256 * i;
            int row = id >> 4, c4 = (id & 15) * 4;
            float4 av = *reinterpret_cast<const float4*>(x + (size_t)(bm + row) * CC + k0 + c4);
            int el = row * 64 + (((c4 >> 3) ^ (row & 7)) * 8) + (c4 & 7);
            float vv[4] = {av.x, av.y, av.z, av.w};
            half4v hi, lo;
#pragma unroll
            for (int e = 0; e < 4; ++e) {
                _Float16 h = (_Float16)vv[e];
                hi[e] = h;
                lo[e] = (_Float16)((vv[e] - (float)h) * 256.0f);
            }
            *reinterpret_cast<half4v*>(&AhiS[el]) = hi;
            *reinterpret_cast<half4v*>(&AloS[el]) = lo;
        }
#pragma unroll
        for (int i = 0; i < 2; ++i) {
            int id = tid + 256 * i;
            int row = id >> 3, dg = id & 7;
            size_t go = (size_t)(bn + row) * CC + k0 + dg * 8;
            half8 wh = *reinterpret_cast<const half8*>(Whi + go);
            half8 wl = *reinterpret_cast<const half8*>(Wlo + go);
            int el = row * 64 + ((dg ^ (row & 7)) * 8);
            *reinterpret_cast<half8*>(&WhiS[el]) = wh;
            *reinterpret_cast<half8*>(&WloS[el]) = wl;
        }
        __syncthreads();
#pragma unroll
        for (int kc = 0; kc < 2; ++kc) {
            const int blk = kc * 4 + g;
            half8 a_hi[2], a_lo[2], b_hi[4], b_lo[4];
#pragma unroll
            for (int mf = 0; mf < 2; ++mf) {
                int row = w * 32 + mf * 16 + n15;
                int el = row * 64 + ((blk ^ (row & 7)) * 8);
                a_hi[mf] = *reinterpret_cast<const half8*>(&AhiS[el]);
                a_lo[mf] = *reinterpret_cast<const half8*>(&AloS[el]);
            }
#pragma unroll
            for (int nt = 0; nt < 4; ++nt) {
                int row = nt * 16 + n15;
                int el = row * 64 + ((blk ^ (row & 7)) * 8);
                b_hi[nt] = *reinterpret_cast<const half8*>(&WhiS[el]);
                b_lo[nt] = *reinterpret_cast<const half8*>(&WloS[el]);
            }
#pragma unroll
            for (int mf = 0; mf < 2; ++mf)
#pragma unroll
                for (int nt = 0; nt < 4; ++nt) {
                    acc_hi[mf][nt] = MFMA16(a_hi[mf], b_hi[nt], acc_hi[mf][nt]);
                    acc_lo[mf][nt] = MFMA16(a_hi[mf], b_lo[nt], acc_lo[mf][nt]);
                    acc_lo[mf][nt] = MFMA16(a_lo[mf], b_hi[nt], acc_lo[mf][nt]);
                }
        }
    }
#pragma unroll
    for (int nt = 0; nt < 4; ++nt) {
        int col = bn + nt * 16 + n15;
        float bc = bias[col];
#pragma unroll
        for (int mf = 0; mf < 2; ++mf)
#pragma unroll
            for (int r = 0; r < 4; ++r) {
                size_t row = bm + w * 32 + mf * 16 + g * 4 + r;
                float y = (acc_hi[mf][nt][r] + acc_lo[mf][nt][r] * (1.0f / 256.0f) + bc) * 0.125f;
                _Float16 h = (_Float16)y;
                Yhi[row * CC + col] = h;
                Ylo[row * CC + col] = (_Float16)((y - (float)h) * 256.0f);
            }
    }
}

// ---------------------------------------------------------------------------
// Fused K-proj + V-proj (A = XR pre-split pair). BM=64 this round:
// grid 64x6x2 = 768 = exactly 3 blocks/CU (was 384 = ragged 1.5/CU).
// blockIdx.z: 0 -> K (f16 single), 1 -> V (transposed Vt[b][c][nk]).
// Per-output math identical to round 15 (bit-exact).
// ---------------------------------------------------------------------------
__global__ __launch_bounds__(256) void gemm_kv(
    const _Float16* __restrict__ Ah, const _Float16* __restrict__ Al,
    const _Float16* __restrict__ Wkh, const _Float16* __restrict__ Wkl,
    const _Float16* __restrict__ Wvh, const _Float16* __restrict__ Wvl,
    const float* __restrict__ bk, const float* __restrict__ bv,
    _Float16* __restrict__ Khi, _Float16* __restrict__ Vt)
{
    __shared__ _Float16 AhiS[64 * 64];
    __shared__ _Float16 AloS[64 * 64];
    __shared__ _Float16 WhiS[64 * 64];
    __shared__ _Float16 WloS[64 * 64];

    const int tid = threadIdx.x;
    const int bm = blockIdx.x * 64;
    const int bn = blockIdx.y * 64;
    const int isV = blockIdx.z;
    const _Float16* Whi = isV ? Wvh : Wkh;
    const _Float16* Wlo = isV ? Wvl : Wkl;
    const float* bias = isV ? bv : bk;
    const int w = tid >> 6, lane = tid & 63;
    const int g = lane >> 4, n15 = lane & 15;

    f32x4 zero4 = {0.f, 0.f, 0.f, 0.f};
    f32x4 acc_hi[4], acc_lo[4];
#pragma unroll
    for (int nt = 0; nt < 4; ++nt) { acc_hi[nt] = zero4; acc_lo[nt] = zero4; }

    for (int k0 = 0; k0 < CC; k0 += 64) {
        __syncthreads();
#pragma unroll
        for (int i = 0; i < 2; ++i) {
            int id = tid + 256 * i;
            int row = id >> 3, dg = id & 7;
            size_t go = (size_t)(bm + row) * CC + k0 + dg * 8;
            half8 hv = *reinterpret_cast<const half8*>(Ah + go);
            half8 lv = *reinterpret_cast<const half8*>(Al + go);
            int el = row * 64 + ((dg ^ (row & 7)) * 8);
            *reinterpret_cast<half8*>(&AhiS[el]) = hv;
            *reinterpret_cast<half8*>(&AloS[el]) = lv;
        }
#pragma unroll
        for (int i = 0; i < 2; ++i) {
            int id = tid + 256 * i;
            int row = id >> 3, dg = id & 7;
            size_t go = (size_t)(bn + row) * CC + k0 + dg * 8;
            half8 wh = *reinterpret_cast<const half8*>(Whi + go);
            half8 wl = *reinterpret_cast<const half8*>(Wlo + go);
            int el = row * 64 + ((dg ^ (row & 7)) * 8);
            *reinterpret_cast<half8*>(&WhiS[el]) = wh;
            *reinterpret_cast<half8*>(&WloS[el]) = wl;
        }
        __syncthreads();
#pragma unroll
        for (int kc = 0; kc < 2; ++kc) {
            const int blk = kc * 4 + g;
            half8 a_hi, a_lo, b_hi[4], b_lo[4];
            {
                int row = w * 16 + n15;
                int el = row * 64 + ((blk ^ (row & 7)) * 8);
                a_hi = *reinterpret_cast<const half8*>(&AhiS[el]);
                a_lo = *reinterpret_cast<const half8*>(&AloS[el]);
            }
#pragma unroll
            for (int nt = 0; nt < 4; ++nt) {
                int row = nt * 16 + n15;
                int el = row * 64 + ((blk ^ (row & 7)) * 8);
                b_hi[nt] = *reinterpret_cast<const half8*>(&WhiS[el]);
                b_lo[nt] = *reinterpret_cast<const half8*>(&WloS[el]);
            }
#pragma unroll
            for (int nt = 0; nt < 4; ++nt) {
                acc_hi[nt] = MFMA16(a_hi, b_hi[nt], acc_hi[nt]);
                acc_lo[nt] = MFMA16(a_hi, b_lo[nt], acc_lo[nt]);
                acc_lo[nt] = MFMA16(a_lo, b_hi[nt], acc_lo[nt]);
            }
        }
    }
#pragma unroll
    for (int nt = 0; nt < 4; ++nt) {
        int col = bn + nt * 16 + n15;
        float bc = bias[col];
#pragma unroll
        for (int r = 0; r < 4; ++r) {
            size_t row = bm + w * 16 + g * 4 + r;
            float y = acc_hi[nt][r] + acc_lo[nt][r] * (1.0f / 256.0f) + bc;
            if (!isV) {
                Khi[row * CC + col] = (_Float16)y;
            } else {
                Vt[((row >> 10) * CC + col) * NKK + (row & 1023)] = (_Float16)y;
            }
        }
    }
}

// ---------------------------------------------------------------------------
// Out-projection GEMM (f16 A, f16 W, f32 out).
// ---------------------------------------------------------------------------
__global__ __launch_bounds__(256) void gemm_out(
    const _Float16* __restrict__ A, const _Float16* __restrict__ Whi,
    const float* __restrict__ bias, float* __restrict__ Yf)
{
    __shared__ _Float16 AhiS[128 * 64];
    __shared__ _Float16 WhiS[64 * 64];

    const int tid = threadIdx.x;
    const int bm = blockIdx.x * 128;
    const int bn = blockIdx.y * 64;
    const int w = tid >> 6, lane = tid & 63;
    const int g = lane >> 4, n15 = lane & 15;

    f32x4 zero4 = {0.f, 0.f, 0.f, 0.f};
    f32x4 acc[2][4];
#pragma unroll
    for (int mf = 0; mf < 2; ++mf)
#pragma unroll
        for (int nt = 0; nt < 4; ++nt) acc[mf][nt] = zero4;

    for (int k0 = 0; k0 < CC; k0 += 64) {
        __syncthreads();
#pragma unroll
        for (int i = 0; i < 4; ++i) {
            int id = tid + 256 * i;
            int row = id >> 3, dg = id & 7;
            half8 av = *reinterpret_cast<const half8*>(A + (size_t)(bm + row) * CC + k0 + dg * 8);
            int el = row * 64 + ((dg ^ (row & 7)) * 8);
            *reinterpret_cast<half8*>(&AhiS[el]) = av;
        }
#pragma unroll
        for (int i = 0; i < 2; ++i) {
            int id = tid + 256 * i;
            int row = id >> 3, dg = id & 7;
            half8 wh = *reinterpret_cast<const half8*>(Whi + (size_t)(bn + row) * CC + k0 + dg * 8);
            int el = row * 64 + ((dg ^ (row & 7)) * 8);
            *reinterpret_cast<half8*>(&WhiS[el]) = wh;
        }
        __syncthreads();
#pragma unroll
        for (int kc = 0; kc < 2; ++kc) {
            const int blk = kc * 4 + g;
            half8 a_hi[2], b_hi[4];
#pragma unroll
            for (int mf = 0; mf < 2; ++mf) {
                int row = w * 32 + mf * 16 + n15;
                a_hi[mf] = *reinterpret_cast<const half8*>(&AhiS[row * 64 + ((blk ^ (row & 7)) * 8)]);
            }
#pragma unroll
            for (int nt = 0; nt < 4; ++nt) {
                int row = nt * 16 + n15;
                b_hi[nt] = *reinterpret_cast<const half8*>(&WhiS[row * 64 + ((blk ^ (row & 7)) * 8)]);
            }
#pragma unroll
            for (int mf = 0; mf < 2; ++mf)
#pragma unroll
                for (int nt = 0; nt < 4; ++nt)
                    acc[mf][nt] = MFMA16(a_hi[mf], b_hi[nt], acc[mf][nt]);
        }
    }
#pragma unroll
    for (int nt = 0; nt < 4; ++nt) {
        int col = bn + nt * 16 + n15;
        float bc = bias[col];
#pragma unroll
        for (int mf = 0; mf < 2; ++mf)
#pragma unroll
            for (int r = 0; r < 4; ++r) {
                size_t row = bm + w * 32 + mf * 16 + g * 4 + r;
                Yf[row * CC + col] = acc[mf][nt][r] + bc;
            }
    }
}

// ---------------------------------------------------------------------------
// Fused: depthwise 2x2/2 conv + LayerNorm (blocks 0..4095) writing f16 pair,
// PLUS weight pre-split (blocks 4096..5247).
// ---------------------------------------------------------------------------
__global__ __launch_bounds__(128)
void srconv_splitw(const float* __restrict__ x, const float* __restrict__ srw,
                   const float* __restrict__ srb, const float* __restrict__ g,
                   const float* __restrict__ beta,
                   _Float16* __restrict__ xrh, _Float16* __restrict__ xrl,
                   const float* __restrict__ Wq, const float* __restrict__ Wk,
                   const float* __restrict__ Wv, const float* __restrict__ Wp,
                   _Float16* __restrict__ wqh, _Float16* __restrict__ wql,
                   _Float16* __restrict__ wkh, _Float16* __restrict__ wkl,
                   _Float16* __restrict__ wvh, _Float16* __restrict__ wvl,
                   _Float16* __restrict__ wph) {
    const int bid = blockIdx.x;
    const int tid = threadIdx.x;
    if (bid >= BB * NKK) {
        int i = (bid - BB * NKK) * 128 + tid;
        float q = Wq[i], k = Wk[i], v = Wv[i], p = Wp[i];
        _Float16 h;
        h = (_Float16)q; wqh[i] = h; wql[i] = (_Float16)((q - (float)h) * 256.0f);
        h = (_Float16)k; wkh[i] = h; wkl[i] = (_Float16)((k - (float)h) * 256.0f);
        h = (_Float16)v; wvh[i] = h; wvl[i] = (_Float16)((v - (float)h) * 256.0f);
        wph[i] = (_Float16)p;
        return;
    }
    const int row = bid;
    const int b  = row >> 10;
    const int nk = row & 1023;
    const int oy = nk >> 5;
    const int ox = nk & 31;
    const int n0 = (2 * oy) * 64 + 2 * ox;
    const float* xb = x + ((size_t)b * NN + n0) * CC;

    float vals[3];
    float lsum = 0.f, lsum2 = 0.f;
#pragma unroll
    for (int i = 0; i < 3; ++i) {
        const int c = tid + i * 128;
        const float4 w = *reinterpret_cast<const float4*>(srw + (size_t)c * 4);
        float v = xb[c] * w.x + xb[CC + c] * w.y +
                  xb[(size_t)64 * CC + c] * w.z + xb[(size_t)65 * CC + c] * w.w + srb[c];
        vals[i] = v;
        lsum += v;
        lsum2 += v * v;
    }
#pragma unroll
    for (int off = 32; off; off >>= 1) {
        lsum  += __shfl_down(lsum, off);
        lsum2 += __shfl_down(lsum2, off);
    }
    __shared__ float ssum[2], ssum2[2];
    if ((tid & 63) == 0) { ssum[tid >> 6] = lsum; ssum2[tid >> 6] = lsum2; }
    __syncthreads();
    const float tot  = ssum[0] + ssum[1];
    const float tot2 = ssum2[0] + ssum2[1];
    const float mu  = tot * (1.0f / 384.0f);
    const float var = tot2 * (1.0f / 384.0f) - mu * mu;
    const float rstd = 1.0f / sqrtf(var + LN_EPS);

    _Float16* oh = xrh + (size_t)row * CC;
    _Float16* ol = xrl + (size_t)row * CC;
#pragma unroll
    for (int i = 0; i < 3; ++i) {
        const int c = tid + i * 128;
        float v = (vals[i] - mu) * rstd * g[c] + beta[c];
        _Float16 h = (_Float16)v;
        oh[c] = h;
        ol[c] = (_Float16)((v - (float)h) * 256.0f);
    }
}

// ---------------------------------------------------------------------------
// Fused MFMA attention v16: v15 (f16 K, 2-MFMA QK^T, triple-buffered,
// 1 barrier/kt, counted vmcnt, deferred l-reduce) + V tile hoisted into
// registers at the top of COMPUTE so PV's B-operands are ~800 cyc ahead of
// their MFMAs (was ~10 cyc -> exposed LDS latency).
// ---------------------------------------------------------------------------
__global__ __launch_bounds__(256, 3)
void attn_mfma(const _Float16* __restrict__ Qhi, const _Float16* __restrict__ Qlo,
               const _Float16* __restrict__ Khi,
               const _Float16* __restrict__ Vt, _Float16* __restrict__ O)
{
    __shared__ _Float16 KhiS[3][32 * 64];   // [key][d]
    __shared__ _Float16 VTS[3][64 * 32];    // [d][key]
    __shared__ _Float16 PWS[4][1024];       // per-wave: 2 frags x [16 q][32 key]

    const int tid = threadIdx.x;
    const int w = tid >> 6, lane = tid & 63;
    const int g = lane >> 4, q15 = lane & 15;
    _Float16* PW = PWS[w];

    const int qt = blockIdx.x, h = blockIdx.y, b = blockIdx.z;

    half8 qh[2][2], ql[2][2];
    {
        size_t qoff = ((size_t)b * NN + qt * 128 + w * 32 + q15) * CC + h * 64 + g * 8;
#pragma unroll
        for (int f = 0; f < 2; ++f) {
            qh[f][0] = *reinterpret_cast<const half8*>(Qhi + qoff + f * 16 * CC);
            qh[f][1] = *reinterpret_cast<const half8*>(Qhi + qoff + f * 16 * CC + 32);
            ql[f][0] = *reinterpret_cast<const half8*>(Qlo + qoff + f * 16 * CC);
            ql[f][1] = *reinterpret_cast<const half8*>(Qlo + qoff + f * 16 * CC + 32);
        }
    }
    asm volatile("s_waitcnt vmcnt(0)" ::: "memory");

    const int krow = tid >> 3, kdg = tid & 7;
    const int kscol = (kdg ^ (krow & 7)) * 8;
    const _Float16* ksrc = Khi + ((size_t)b * NKK + krow) * CC + h * 64 + kscol;
    const int vd = tid >> 2, vkb = tid & 3;
    const _Float16* vsrc = Vt + ((size_t)b * CC + h * 64 + vd) * NKK + ((vkb ^ ((vd >> 1) & 3)) * 8);

    f32x4 zero4 = {0.f, 0.f, 0.f, 0.f};
    f32x4 o[2][4];
#pragma unroll
    for (int f = 0; f < 2; ++f)
#pragma unroll
        for (int nt = 0; nt < 4; ++nt) o[f][nt] = zero4;
    float l[2] = {0.f, 0.f};

#define ISSUE(kt, buf)                                                        \
    {                                                                         \
        GLL16(ksrc + (size_t)(kt) * 32 * CC, &KhiS[buf][tid * 8]);            \
        GLL16(vsrc + (kt) * 32,              &VTS[buf][tid * 8]);             \
    }

    auto COMPUTE = [&](const _Float16* KH, const _Float16* VT) {
        // ---- hoist V B-frags into registers (covered by QK^T + softmax)
        half8 vb[4];
#pragma unroll
        for (int nt = 0; nt < 4; ++nt) {
            int d = nt * 16 + q15;
            vb[nt] = *reinterpret_cast<const half8*>(&VT[d * 32 + ((g ^ ((d >> 1) & 3)) * 8)]);
        }
#pragma unroll
        for (int mt = 0; mt < 2; ++mt) {
            f32x4 sh[2], sl[2];
#pragma unroll
            for (int f = 0; f < 2; ++f) { sh[f] = zero4; sl[f] = zero4; }
            __builtin_amdgcn_s_setprio(1);
#pragma unroll
            for (int kc = 0; kc < 2; ++kc) {
                int key = mt * 16 + q15;
                int el = key * 64 + (((kc * 4 + g) ^ (key & 7)) * 8);
                half8 ah = *reinterpret_cast<const half8*>(&KH[el]);
#pragma unroll
                for (int f = 0; f < 2; ++f) {
                    sh[f] = MFMA16(ah, qh[f][kc], sh[f]);
                    sl[f] = MFMA16(ah, ql[f][kc], sl[f]);
                }
            }
            __builtin_amdgcn_s_setprio(0);
            int elw = q15 * 32 + (((mt * 2 + (g >> 1)) ^ ((q15 >> 1) & 3)) * 8) + (g & 1) * 4;
#pragma unroll
            for (int f = 0; f < 2; ++f) {
                half4v pk;
#pragma unroll
                for (int r = 0; r < 4; ++r) {
                    float sv = sh[f][r] + sl[f][r] * (1.0f / 256.0f);
                    float e = __expf(fabsf(sv));
                    l[f] += e;
                    pk[r] = (_Float16)__builtin_copysignf(e, sv);
                }
                *reinterpret_cast<half4v*>(&PW[elw + f * 512]) = pk;
            }
        }

        __builtin_amdgcn_s_setprio(1);
        {
            int pel = q15 * 32 + ((g ^ ((q15 >> 1) & 3)) * 8);
            half8 pa0 = *reinterpret_cast<const half8*>(&PW[pel]);
            half8 pa1 = *reinterpret_cast<const half8*>(&PW[pel + 512]);
#pragma unroll
            for (int nt = 0; nt < 4; ++nt) {
                o[0][nt] = MFMA16(pa0, vb[nt], o[0][nt]);
                o[1][nt] = MFMA16(pa1, vb[nt], o[1][nt]);
            }
        }
        __builtin_amdgcn_s_setprio(0);
    };

    ISSUE(0, 0);
    ISSUE(1, 1);

#pragma unroll 1
    for (int base = 0; base < 30; base += 3) {
        asm volatile("s_waitcnt vmcnt(2)" ::: "memory");
        __builtin_amdgcn_s_barrier();
        COMPUTE(KhiS[0], VTS[0]);
        ISSUE(base + 2, 2);

        asm volatile("s_waitcnt vmcnt(2)" ::: "memory");
        __builtin_amdgcn_s_barrier();
        COMPUTE(KhiS[1], VTS[1]);
        ISSUE(base + 3, 0);

        asm volatile("s_waitcnt vmcnt(2)" ::: "memory");
        __builtin_amdgcn_s_barrier();
        COMPUTE(KhiS[2], VTS[2]);
        if (base + 4 < 32) ISSUE(base + 4, 1);
    }
    asm volatile("s_waitcnt vmcnt(2)" ::: "memory");
    __builtin_amdgcn_s_barrier();
    COMPUTE(KhiS[0], VTS[0]);
    asm volatile("s_waitcnt vmcnt(0)" ::: "memory");
    __builtin_amdgcn_s_barrier();
    COMPUTE(KhiS[1], VTS[1]);
#undef ISSUE

#pragma unroll
    for (int f = 0; f < 2; ++f) {
        l[f] += __shfl_xor(l[f], 16);
        l[f] += __shfl_xor(l[f], 32);
    }
#pragma unroll
    for (int f = 0; f < 2; ++f) {
        float rl = 1.0f / l[f];
        float rlq[4];
#pragma unroll
        for (int r = 0; r < 4; ++r) rlq[r] = __shfl(rl, g * 4 + r);
#pragma unroll
        for (int nt = 0; nt < 4; ++nt)
#pragma unroll
            for (int r = 0; r < 4; ++r) {
                size_t row = (size_t)b * NN + qt * 128 + w * 32 + f * 16 + g * 4 + r;
                O[row * CC + h * 64 + nt * 16 + q15] = (_Float16)(o[f][nt][r] * rlq[r]);
            }
    }
}

// ---------------------------------------------------------------------------
extern "C" void kernel_launch(void* const* d_in, const int* in_sizes, int n_in,
                              void* d_out, int out_size, void* d_ws, size_t ws_size,
                              hipStream_t stream) {
    const float* x   = (const float*)d_in[0];
    const float* Wq  = (const float*)d_in[1];
    const float* bq  = (const float*)d_in[2];
    const float* Wk  = (const float*)d_in[3];
    const float* bk  = (const float*)d_in[4];
    const float* Wv  = (const float*)d_in[5];
    const float* bv  = (const float*)d_in[6];
    const float* srw = (const float*)d_in[7];
    const float* srb = (const float*)d_in[8];
    const float* lng = (const float*)d_in[9];
    const float* lnb = (const float*)d_in[10];
    const float* Wp  = (const float*)d_in[11];
    const float* bp  = (const float*)d_in[12];
    float* out = (float*)d_out;

    // workspace layout (~40 MB)
    char* wsb = (char*)d_ws;
    _Float16* Qhi  = (_Float16*)wsb;                   // 12.58 MB
    _Float16* Qlo  = (_Float16*)(wsb + 12582912);      // 12.58 MB (also attn O)
    _Float16* XRhi = (_Float16*)(wsb + 25165824);      // 3.15 MB
    _Float16* XRlo = (_Float16*)(wsb + 28311552);      // 3.15 MB
    _Float16* Khi  = (_Float16*)(wsb + 31457280);      // 3.15 MB
    _Float16* Vt   = (_Float16*)(wsb + 34603008);      // 3.15 MB [b][c][nk]
    _Float16* Wqh  = (_Float16*)(wsb + 37748736);      // 7 x 0.295 MB
    _Float16* Wql  = Wqh + 147456;
    _Float16* Wkh  = Wql + 147456;
    _Float16* Wkl  = Wkh + 147456;
    _Float16* Wvh  = Wkl + 147456;
    _Float16* Wvl  = Wvh + 147456;
    _Float16* Wph  = Wvl + 147456;
    _Float16* Ob   = Qlo;

    // 1) conv + LN -> pre-split pair, fused with weight pre-split
    srconv_splitw<<<dim3(BB * NKK + 1152), dim3(128), 0, stream>>>(
        x, srw, srb, lng, lnb, XRhi, XRlo,
        Wq, Wk, Wv, Wp, Wqh, Wql, Wkh, Wkl, Wvh, Wvl, Wph);
    // 2) Q projection (768 blocks = exactly 3/CU)
    gemm_q<<<dim3(128, 6), 256, 0, stream>>>(x, Wqh, Wql, bq, Qhi, Qlo);
    // 3) fused K + V projections (BM=64: 768 blocks = 3/CU uniform)
    gemm_kv<<<dim3(64, 6, 2), 256, 0, stream>>>(
        XRhi, XRlo, Wkh, Wkl, Wvh, Wvl, bk, bv, Khi, Vt);
    // 4) fused attention (v16: f16 K + hoisted V regs)
    attn_mfma<<<dim3(32, 6, 4), 256, 0, stream>>>(Qhi, Qlo, Khi, Vt, Ob);
    // 5) output projection -> d_out (f32)
    gemm_out<<<dim3(128, 6), 256, 0, stream>>>(Ob, Wph, bp, out);
}

// Round 17
// 114.452 us; speedup vs baseline: 1.0114x; 1.0114x over previous
//
#include <hip/hip_runtime.h>
#include <hip/hip_bf16.h>
#include <math.h>

#define BB 4
#define NN 4096
#define CC 384
#define NHH 6
#define HDD 64
#define NKK 1024
#define LN_EPS 1e-5f

typedef _Float16 half8 __attribute__((ext_vector_type(8)));
typedef _Float16 half4v __attribute__((ext_vector_type(4)));
typedef _Float16 half2v __attribute__((ext_vector_type(2)));
typedef float f32x4 __attribute__((ext_vector_type(4)));

#define MFMA16(a, b, c) __builtin_amdgcn_mfma_f32_16x16x32_f16((a), (b), (c), 0, 0, 0)

#define GLL16(src, dst)                                                       \
    __builtin_amdgcn_global_load_lds(                                         \
        (const __attribute__((address_space(1))) void*)(src),                 \
        (__attribute__((address_space(3))) void*)(dst), 16, 0, 0)

// ---------------------------------------------------------------------------
// Q projection: A = x (f32, split on stage), W = pre-split pair,
// Y = (x @ Wq^T + bq) * 0.125 as f16 hi/lo pair. 768 blocks = 3/CU.
// ---------------------------------------------------------------------------
__global__ __launch_bounds__(256) void gemm_q(
    const float* __restrict__ x,
    const _Float16* __restrict__ Whi, const _Float16* __restrict__ Wlo,
    const float* __restrict__ bias,
    _Float16* __restrict__ Yhi, _Float16* __restrict__ Ylo)
{
    __shared__ _Float16 AhiS[128 * 64];
    __shared__ _Float16 AloS[128 * 64];
    __shared__ _Float16 WhiS[64 * 64];
    __shared__ _Float16 WloS[64 * 64];

    const int tid = threadIdx.x;
    const int bm = blockIdx.x * 128;
    const int bn = blockIdx.y * 64;
    const int w = tid >> 6, lane = tid & 63;
    const int g = lane >> 4, n15 = lane & 15;

    f32x4 zero4 = {0.f, 0.f, 0.f, 0.f};
    f32x4 acc_hi[2][4], acc_lo[2][4];
#pragma unroll
    for (int mf = 0; mf < 2; ++mf)
#pragma unroll
        for (int nt = 0; nt < 4; ++nt) { acc_hi[mf][nt] = zero4; acc_lo[mf][nt] = zero4; }

    for (int k0 = 0; k0 < CC; k0 += 64) {
        __syncthreads();
#pragma unroll
        for (int i = 0; i < 8; ++i) {
            int id = tid + 256 * i;
            int row = id >> 4, c4 = (id & 15) * 4;
            float4 av = *reinterpret_cast<const float4*>(x + (size_t)(bm + row) * CC + k0 + c4);
            int el = row * 64 + (((c4 >> 3) ^ (row & 7)) * 8) + (c4 & 7);
            float vv[4] = {av.x, av.y, av.z, av.w};
            half4v hi, lo;
#pragma unroll
            for (int e = 0; e < 4; ++e) {
                _Float16 h = (_Float16)vv[e];
                hi[e] = h;
                lo[e] = (_Float16)((vv[e] - (float)h) * 256.0f);
            }
            *reinterpret_cast<half4v*>(&AhiS[el]) = hi;
            *reinterpret_cast<half4v*>(&AloS[el]) = lo;
        }
#pragma unroll
        for (int i = 0; i < 2; ++i) {
            int id = tid + 256 * i;
            int row = id >> 3, dg = id & 7;
            size_t go = (size_t)(bn + row) * CC + k0 + dg * 8;
            half8 wh = *reinterpret_cast<const half8*>(Whi + go);
            half8 wl = *reinterpret_cast<const half8*>(Wlo + go);
            int el = row * 64 + ((dg ^ (row & 7)) * 8);
            *reinterpret_cast<half8*>(&WhiS[el]) = wh;
            *reinterpret_cast<half8*>(&WloS[el]) = wl;
        }
        __syncthreads();
#pragma unroll
        for (int kc = 0; kc < 2; ++kc) {
            const int blk = kc * 4 + g;
            half8 a_hi[2], a_lo[2], b_hi[4], b_lo[4];
#pragma unroll
            for (int mf = 0; mf < 2; ++mf) {
                int row = w * 32 + mf * 16 + n15;
                int el = row * 64 + ((blk ^ (row & 7)) * 8);
                a_hi[mf] = *reinterpret_cast<const half8*>(&AhiS[el]);
                a_lo[mf] = *reinterpret_cast<const half8*>(&AloS[el]);
            }
#pragma unroll
            for (int nt = 0; nt < 4; ++nt) {
                int row = nt * 16 + n15;
                int el = row * 64 + ((blk ^ (row & 7)) * 8);
                b_hi[nt] = *reinterpret_cast<const half8*>(&WhiS[el]);
                b_lo[nt] = *reinterpret_cast<const half8*>(&WloS[el]);
            }
#pragma unroll
            for (int mf = 0; mf < 2; ++mf)
#pragma unroll
                for (int nt = 0; nt < 4; ++nt) {
                    acc_hi[mf][nt] = MFMA16(a_hi[mf], b_hi[nt], acc_hi[mf][nt]);
                    acc_lo[mf][nt] = MFMA16(a_hi[mf], b_lo[nt], acc_lo[mf][nt]);
                    acc_lo[mf][nt] = MFMA16(a_lo[mf], b_hi[nt], acc_lo[mf][nt]);
                }
        }
    }
#pragma unroll
    for (int nt = 0; nt < 4; ++nt) {
        int col = bn + nt * 16 + n15;
        float bc = bias[col];
#pragma unroll
        for (int mf = 0; mf < 2; ++mf)
#pragma unroll
            for (int r = 0; r < 4; ++r) {
                size_t row = bm + w * 32 + mf * 16 + g * 4 + r;
                float y = (acc_hi[mf][nt][r] + acc_lo[mf][nt][r] * (1.0f / 256.0f) + bc) * 0.125f;
                _Float16 h = (_Float16)y;
                Yhi[row * CC + col] = h;
                Ylo[row * CC + col] = (_Float16)((y - (float)h) * 256.0f);
            }
    }
}

// ---------------------------------------------------------------------------
// Fused K-proj + V-proj (A = XR pre-split pair), BM=128 (round-15 proven —
// BM=64 regressed: W-panel reuse halved). blockIdx.z: 0 -> K (f16 single),
// 1 -> V (transposed Vt[b][c][nk]).
// ---------------------------------------------------------------------------
__global__ __launch_bounds__(256) void gemm_kv(
    const _Float16* __restrict__ Ah, const _Float16* __restrict__ Al,
    const _Float16* __restrict__ Wkh, const _Float16* __restrict__ Wkl,
    const _Float16* __restrict__ Wvh, const _Float16* __restrict__ Wvl,
    const float* __restrict__ bk, const float* __restrict__ bv,
    _Float16* __restrict__ Khi, _Float16* __restrict__ Vt)
{
    __shared__ _Float16 AhiS[128 * 64];
    __shared__ _Float16 AloS[128 * 64];
    __shared__ _Float16 WhiS[64 * 64];
    __shared__ _Float16 WloS[64 * 64];

    const int tid = threadIdx.x;
    const int bm = blockIdx.x * 128;
    const int bn = blockIdx.y * 64;
    const int isV = blockIdx.z;
    const _Float16* Whi = isV ? Wvh : Wkh;
    const _Float16* Wlo = isV ? Wvl : Wkl;
    const float* bias = isV ? bv : bk;
    const int w = tid >> 6, lane = tid & 63;
    const int g = lane >> 4, n15 = lane & 15;

    f32x4 zero4 = {0.f, 0.f, 0.f, 0.f};
    f32x4 acc_hi[2][4], acc_lo[2][4];
#pragma unroll
    for (int mf = 0; mf < 2; ++mf)
#pragma unroll
        for (int nt = 0; nt < 4; ++nt) { acc_hi[mf][nt] = zero4; acc_lo[mf][nt] = zero4; }

    for (int k0 = 0; k0 < CC; k0 += 64) {
        __syncthreads();
#pragma unroll
        for (int i = 0; i < 4; ++i) {
            int id = tid + 256 * i;
            int row = id >> 3, dg = id & 7;
            size_t go = (size_t)(bm + row) * CC + k0 + dg * 8;
            half8 hv = *reinterpret_cast<const half8*>(Ah + go);
            half8 lv = *reinterpret_cast<const half8*>(Al + go);
            int el = row * 64 + ((dg ^ (row & 7)) * 8);
            *reinterpret_cast<half8*>(&AhiS[el]) = hv;
            *reinterpret_cast<half8*>(&AloS[el]) = lv;
        }
#pragma unroll
        for (int i = 0; i < 2; ++i) {
            int id = tid + 256 * i;
            int row = id >> 3, dg = id & 7;
            size_t go = (size_t)(bn + row) * CC + k0 + dg * 8;
            half8 wh = *reinterpret_cast<const half8*>(Whi + go);
            half8 wl = *reinterpret_cast<const half8*>(Wlo + go);
            int el = row * 64 + ((dg ^ (row & 7)) * 8);
            *reinterpret_cast<half8*>(&WhiS[el]) = wh;
            *reinterpret_cast<half8*>(&WloS[el]) = wl;
        }
        __syncthreads();
#pragma unroll
        for (int kc = 0; kc < 2; ++kc) {
            const int blk = kc * 4 + g;
            half8 a_hi[2], a_lo[2], b_hi[4], b_lo[4];
#pragma unroll
            for (int mf = 0; mf < 2; ++mf) {
                int row = w * 32 + mf * 16 + n15;
                int el = row * 64 + ((blk ^ (row & 7)) * 8);
                a_hi[mf] = *reinterpret_cast<const half8*>(&AhiS[el]);
                a_lo[mf] = *reinterpret_cast<const half8*>(&AloS[el]);
            }
#pragma unroll
            for (int nt = 0; nt < 4; ++nt) {
                int row = nt * 16 + n15;
                int el = row * 64 + ((blk ^ (row & 7)) * 8);
                b_hi[nt] = *reinterpret_cast<const half8*>(&WhiS[el]);
                b_lo[nt] = *reinterpret_cast<const half8*>(&WloS[el]);
            }
#pragma unroll
            for (int mf = 0; mf < 2; ++mf)
#pragma unroll
                for (int nt = 0; nt < 4; ++nt) {
                    acc_hi[mf][nt] = MFMA16(a_hi[mf], b_hi[nt], acc_hi[mf][nt]);
                    acc_lo[mf][nt] = MFMA16(a_hi[mf], b_lo[nt], acc_lo[mf][nt]);
                    acc_lo[mf][nt] = MFMA16(a_lo[mf], b_hi[nt], acc_lo[mf][nt]);
                }
        }
    }
#pragma unroll
    for (int nt = 0; nt < 4; ++nt) {
        int col = bn + nt * 16 + n15;
        float bc = bias[col];
#pragma unroll
        for (int mf = 0; mf < 2; ++mf)
#pragma unroll
            for (int r = 0; r < 4; ++r) {
                size_t row = bm + w * 32 + mf * 16 + g * 4 + r;
                float y = acc_hi[mf][nt][r] + acc_lo[mf][nt][r] * (1.0f / 256.0f) + bc;
                if (!isV) {
                    Khi[row * CC + col] = (_Float16)y;
                } else {
                    Vt[((row >> 10) * CC + col) * NKK + (row & 1023)] = (_Float16)y;
                }
            }
    }
}

// ---------------------------------------------------------------------------
// Out-projection GEMM (f16 A, f16 W, f32 out).
// ---------------------------------------------------------------------------
__global__ __launch_bounds__(256) void gemm_out(
    const _Float16* __restrict__ A, const _Float16* __restrict__ Whi,
    const float* __restrict__ bias, float* __restrict__ Yf)
{
    __shared__ _Float16 AhiS[128 * 64];
    __shared__ _Float16 WhiS[64 * 64];

    const int tid = threadIdx.x;
    const int bm = blockIdx.x * 128;
    const int bn = blockIdx.y * 64;
    const int w = tid >> 6, lane = tid & 63;
    const int g = lane >> 4, n15 = lane & 15;

    f32x4 zero4 = {0.f, 0.f, 0.f, 0.f};
    f32x4 acc[2][4];
#pragma unroll
    for (int mf = 0; mf < 2; ++mf)
#pragma unroll
        for (int nt = 0; nt < 4; ++nt) acc[mf][nt] = zero4;

    for (int k0 = 0; k0 < CC; k0 += 64) {
        __syncthreads();
#pragma unroll
        for (int i = 0; i < 4; ++i) {
            int id = tid + 256 * i;
            int row = id >> 3, dg = id & 7;
            half8 av = *reinterpret_cast<const half8*>(A + (size_t)(bm + row) * CC + k0 + dg * 8);
            int el = row * 64 + ((dg ^ (row & 7)) * 8);
            *reinterpret_cast<half8*>(&AhiS[el]) = av;
        }
#pragma unroll
        for (int i = 0; i < 2; ++i) {
            int id = tid + 256 * i;
            int row = id >> 3, dg = id & 7;
            half8 wh = *reinterpret_cast<const half8*>(Whi + (size_t)(bn + row) * CC + k0 + dg * 8);
            int el = row * 64 + ((dg ^ (row & 7)) * 8);
            *reinterpret_cast<half8*>(&WhiS[el]) = wh;
        }
        __syncthreads();
#pragma unroll
        for (int kc = 0; kc < 2; ++kc) {
            const int blk = kc * 4 + g;
            half8 a_hi[2], b_hi[4];
#pragma unroll
            for (int mf = 0; mf < 2; ++mf) {
                int row = w * 32 + mf * 16 + n15;
                a_hi[mf] = *reinterpret_cast<const half8*>(&AhiS[row * 64 + ((blk ^ (row & 7)) * 8)]);
            }
#pragma unroll
            for (int nt = 0; nt < 4; ++nt) {
                int row = nt * 16 + n15;
                b_hi[nt] = *reinterpret_cast<const half8*>(&WhiS[row * 64 + ((blk ^ (row & 7)) * 8)]);
            }
#pragma unroll
            for (int mf = 0; mf < 2; ++mf)
#pragma unroll
                for (int nt = 0; nt < 4; ++nt)
                    acc[mf][nt] = MFMA16(a_hi[mf], b_hi[nt], acc[mf][nt]);
        }
    }
#pragma unroll
    for (int nt = 0; nt < 4; ++nt) {
        int col = bn + nt * 16 + n15;
        float bc = bias[col];
#pragma unroll
        for (int mf = 0; mf < 2; ++mf)
#pragma unroll
            for (int r = 0; r < 4; ++r) {
                size_t row = bm + w * 32 + mf * 16 + g * 4 + r;
                Yf[row * CC + col] = acc[mf][nt][r] + bc;
            }
    }
}

// ---------------------------------------------------------------------------
// Fused: depthwise 2x2/2 conv + LayerNorm (blocks 0..4095) writing f16 pair,
// PLUS weight pre-split (blocks 4096..5247).
// ---------------------------------------------------------------------------
__global__ __launch_bounds__(128)
void srconv_splitw(const float* __restrict__ x, const float* __restrict__ srw,
                   const float* __restrict__ srb, const float* __restrict__ g,
                   const float* __restrict__ beta,
                   _Float16* __restrict__ xrh, _Float16* __restrict__ xrl,
                   const float* __restrict__ Wq, const float* __restrict__ Wk,
                   const float* __restrict__ Wv, const float* __restrict__ Wp,
                   _Float16* __restrict__ wqh, _Float16* __restrict__ wql,
                   _Float16* __restrict__ wkh, _Float16* __restrict__ wkl,
                   _Float16* __restrict__ wvh, _Float16* __restrict__ wvl,
                   _Float16* __restrict__ wph) {
    const int bid = blockIdx.x;
    const int tid = threadIdx.x;
    if (bid >= BB * NKK) {
        int i = (bid - BB * NKK) * 128 + tid;
        float q = Wq[i], k = Wk[i], v = Wv[i], p = Wp[i];
        _Float16 h;
        h = (_Float16)q; wqh[i] = h; wql[i] = (_Float16)((q - (float)h) * 256.0f);
        h = (_Float16)k; wkh[i] = h; wkl[i] = (_Float16)((k - (float)h) * 256.0f);
        h = (_Float16)v; wvh[i] = h; wvl[i] = (_Float16)((v - (float)h) * 256.0f);
        wph[i] = (_Float16)p;
        return;
    }
    const int row = bid;
    const int b  = row >> 10;
    const int nk = row & 1023;
    const int oy = nk >> 5;
    const int ox = nk & 31;
    const int n0 = (2 * oy) * 64 + 2 * ox;
    const float* xb = x + ((size_t)b * NN + n0) * CC;

    float vals[3];
    float lsum = 0.f, lsum2 = 0.f;
#pragma unroll
    for (int i = 0; i < 3; ++i) {
        const int c = tid + i * 128;
        const float4 w = *reinterpret_cast<const float4*>(srw + (size_t)c * 4);
        float v = xb[c] * w.x + xb[CC + c] * w.y +
                  xb[(size_t)64 * CC + c] * w.z + xb[(size_t)65 * CC + c] * w.w + srb[c];
        vals[i] = v;
        lsum += v;
        lsum2 += v * v;
    }
#pragma unroll
    for (int off = 32; off; off >>= 1) {
        lsum  += __shfl_down(lsum, off);
        lsum2 += __shfl_down(lsum2, off);
    }
    __shared__ float ssum[2], ssum2[2];
    if ((tid & 63) == 0) { ssum[tid >> 6] = lsum; ssum2[tid >> 6] = lsum2; }
    __syncthreads();
    const float tot  = ssum[0] + ssum[1];
    const float tot2 = ssum2[0] + ssum2[1];
    const float mu  = tot * (1.0f / 384.0f);
    const float var = tot2 * (1.0f / 384.0f) - mu * mu;
    const float rstd = 1.0f / sqrtf(var + LN_EPS);

    _Float16* oh = xrh + (size_t)row * CC;
    _Float16* ol = xrl + (size_t)row * CC;
#pragma unroll
    for (int i = 0; i < 3; ++i) {
        const int c = tid + i * 128;
        float v = (vals[i] - mu) * rstd * g[c] + beta[c];
        _Float16 h = (_Float16)v;
        oh[c] = h;
        ol[c] = (_Float16)((v - (float)h) * 256.0f);
    }
}

// ---------------------------------------------------------------------------
// Fused MFMA attention v17: v16 (f16 K, 2-MFMA QK^T, V hoisted to regs,
// triple-buffered, 1 barrier/kt, counted vmcnt, deferred l-reduce) with
// setprio REMOVED from the QK^T cluster (lockstep structure: pinning the
// MFMA burst prevents softmax-VALU/MFMA interleave across mt groups);
// setprio kept on PV (pure-MFMA, nothing to interleave).
// ---------------------------------------------------------------------------
__global__ __launch_bounds__(256, 3)
void attn_mfma(const _Float16* __restrict__ Qhi, const _Float16* __restrict__ Qlo,
               const _Float16* __restrict__ Khi,
               const _Float16* __restrict__ Vt, _Float16* __restrict__ O)
{
    __shared__ _Float16 KhiS[3][32 * 64];   // [key][d]
    __shared__ _Float16 VTS[3][64 * 32];    // [d][key]
    __shared__ _Float16 PWS[4][1024];       // per-wave: 2 frags x [16 q][32 key]

    const int tid = threadIdx.x;
    const int w = tid >> 6, lane = tid & 63;
    const int g = lane >> 4, q15 = lane & 15;
    _Float16* PW = PWS[w];

    const int qt = blockIdx.x, h = blockIdx.y, b = blockIdx.z;

    half8 qh[2][2], ql[2][2];
    {
        size_t qoff = ((size_t)b * NN + qt * 128 + w * 32 + q15) * CC + h * 64 + g * 8;
#pragma unroll
        for (int f = 0; f < 2; ++f) {
            qh[f][0] = *reinterpret_cast<const half8*>(Qhi + qoff + f * 16 * CC);
            qh[f][1] = *reinterpret_cast<const half8*>(Qhi + qoff + f * 16 * CC + 32);
            ql[f][0] = *reinterpret_cast<const half8*>(Qlo + qoff + f * 16 * CC);
            ql[f][1] = *reinterpret_cast<const half8*>(Qlo + qoff + f * 16 * CC + 32);
        }
    }
    asm volatile("s_waitcnt vmcnt(0)" ::: "memory");

    const int krow = tid >> 3, kdg = tid & 7;
    const int kscol = (kdg ^ (krow & 7)) * 8;
    const _Float16* ksrc = Khi + ((size_t)b * NKK + krow) * CC + h * 64 + kscol;
    const int vd = tid >> 2, vkb = tid & 3;
    const _Float16* vsrc = Vt + ((size_t)b * CC + h * 64 + vd) * NKK + ((vkb ^ ((vd >> 1) & 3)) * 8);

    f32x4 zero4 = {0.f, 0.f, 0.f, 0.f};
    f32x4 o[2][4];
#pragma unroll
    for (int f = 0; f < 2; ++f)
#pragma unroll
        for (int nt = 0; nt < 4; ++nt) o[f][nt] = zero4;
    float l[2] = {0.f, 0.f};

#define ISSUE(kt, buf)                                                        \
    {                                                                         \
        GLL16(ksrc + (size_t)(kt) * 32 * CC, &KhiS[buf][tid * 8]);            \
        GLL16(vsrc + (kt) * 32,              &VTS[buf][tid * 8]);             \
    }

    auto COMPUTE = [&](const _Float16* KH, const _Float16* VT) {
        // ---- hoist V B-frags into registers (covered by QK^T + softmax)
        half8 vb[4];
#pragma unroll
        for (int nt = 0; nt < 4; ++nt) {
            int d = nt * 16 + q15;
            vb[nt] = *reinterpret_cast<const half8*>(&VT[d * 32 + ((g ^ ((d >> 1) & 3)) * 8)]);
        }
#pragma unroll
        for (int mt = 0; mt < 2; ++mt) {
            f32x4 sh[2], sl[2];
#pragma unroll
            for (int f = 0; f < 2; ++f) { sh[f] = zero4; sl[f] = zero4; }
#pragma unroll
            for (int kc = 0; kc < 2; ++kc) {
                int key = mt * 16 + q15;
                int el = key * 64 + (((kc * 4 + g) ^ (key & 7)) * 8);
                half8 ah = *reinterpret_cast<const half8*>(&KH[el]);
#pragma unroll
                for (int f = 0; f < 2; ++f) {
                    sh[f] = MFMA16(ah, qh[f][kc], sh[f]);
                    sl[f] = MFMA16(ah, ql[f][kc], sl[f]);
                }
            }
            int elw = q15 * 32 + (((mt * 2 + (g >> 1)) ^ ((q15 >> 1) & 3)) * 8) + (g & 1) * 4;
#pragma unroll
            for (int f = 0; f < 2; ++f) {
                half4v pk;
#pragma unroll
                for (int r = 0; r < 4; ++r) {
                    float sv = sh[f][r] + sl[f][r] * (1.0f / 256.0f);
                    float e = __expf(fabsf(sv));
                    l[f] += e;
                    pk[r] = (_Float16)__builtin_copysignf(e, sv);
                }
                *reinterpret_cast<half4v*>(&PW[elw + f * 512]) = pk;
            }
        }

        __builtin_amdgcn_s_setprio(1);
        {
            int pel = q15 * 32 + ((g ^ ((q15 >> 1) & 3)) * 8);
            half8 pa0 = *reinterpret_cast<const half8*>(&PW[pel]);
            half8 pa1 = *reinterpret_cast<const half8*>(&PW[pel + 512]);
#pragma unroll
            for (int nt = 0; nt < 4; ++nt) {
                o[0][nt] = MFMA16(pa0, vb[nt], o[0][nt]);
                o[1][nt] = MFMA16(pa1, vb[nt], o[1][nt]);
            }
        }
        __builtin_amdgcn_s_setprio(0);
    };

    ISSUE(0, 0);
    ISSUE(1, 1);

#pragma unroll 1
    for (int base = 0; base < 30; base += 3) {
        asm volatile("s_waitcnt vmcnt(2)" ::: "memory");
        __builtin_amdgcn_s_barrier();
        COMPUTE(KhiS[0], VTS[0]);
        ISSUE(base + 2, 2);

        asm volatile("s_waitcnt vmcnt(2)" ::: "memory");
        __builtin_amdgcn_s_barrier();
        COMPUTE(KhiS[1], VTS[1]);
        ISSUE(base + 3, 0);

        asm volatile("s_waitcnt vmcnt(2)" ::: "memory");
        __builtin_amdgcn_s_barrier();
        COMPUTE(KhiS[2], VTS[2]);
        if (base + 4 < 32) ISSUE(base + 4, 1);
    }
    asm volatile("s_waitcnt vmcnt(2)" ::: "memory");
    __builtin_amdgcn_s_barrier();
    COMPUTE(KhiS[0], VTS[0]);
    asm volatile("s_waitcnt vmcnt(0)" ::: "memory");
    __builtin_amdgcn_s_barrier();
    COMPUTE(KhiS[1], VTS[1]);
#undef ISSUE

#pragma unroll
    for (int f = 0; f < 2; ++f) {
        l[f] += __shfl_xor(l[f], 16);
        l[f] += __shfl_xor(l[f], 32);
    }
#pragma unroll
    for (int f = 0; f < 2; ++f) {
        float rl = 1.0f / l[f];
        float rlq[4];
#pragma unroll
        for (int r = 0; r < 4; ++r) rlq[r] = __shfl(rl, g * 4 + r);
#pragma unroll
        for (int nt = 0; nt < 4; ++nt)
#pragma unroll
            for (int r = 0; r < 4; ++r) {
                size_t row = (size_t)b * NN + qt * 128 + w * 32 + f * 16 + g * 4 + r;
                O[row * CC + h * 64 + nt * 16 + q15] = (_Float16)(o[f][nt][r] * rlq[r]);
            }
    }
}

// ---------------------------------------------------------------------------
extern "C" void kernel_launch(void* const* d_in, const int* in_sizes, int n_in,
                              void* d_out, int out_size, void* d_ws, size_t ws_size,
                              hipStream_t stream) {
    const float* x   = (const float*)d_in[0];
    const float* Wq  = (const float*)d_in[1];
    const float* bq  = (const float*)d_in[2];
    const float* Wk  = (const float*)d_in[3];
    const float* bk  = (const float*)d_in[4];
    const float* Wv  = (const float*)d_in[5];
    const float* bv  = (const float*)d_in[6];
    const float* srw = (const float*)d_in[7];
    const float* srb = (const float*)d_in[8];
    const float* lng = (const float*)d_in[9];
    const float* lnb = (const float*)d_in[10];
    const float* Wp  = (const float*)d_in[11];
    const float* bp  = (const float*)d_in[12];
    float* out = (float*)d_out;

    // workspace layout (~40 MB)
    char* wsb = (char*)d_ws;
    _Float16* Qhi  = (_Float16*)wsb;                   // 12.58 MB
    _Float16* Qlo  = (_Float16*)(wsb + 12582912);      // 12.58 MB (also attn O)
    _Float16* XRhi = (_Float16*)(wsb + 25165824);      // 3.15 MB
    _Float16* XRlo = (_Float16*)(wsb + 28311552);      // 3.15 MB
    _Float16* Khi  = (_Float16*)(wsb + 31457280);      // 3.15 MB
    _Float16* Vt   = (_Float16*)(wsb + 34603008);      // 3.15 MB [b][c][nk]
    _Float16* Wqh  = (_Float16*)(wsb + 37748736);      // 7 x 0.295 MB
    _Float16* Wql  = Wqh + 147456;
    _Float16* Wkh  = Wql + 147456;
    _Float16* Wkl  = Wkh + 147456;
    _Float16* Wvh  = Wkl + 147456;
    _Float16* Wvl  = Wvh + 147456;
    _Float16* Wph  = Wvl + 147456;
    _Float16* Ob   = Qlo;

    // 1) conv + LN -> pre-split pair, fused with weight pre-split
    srconv_splitw<<<dim3(BB * NKK + 1152), dim3(128), 0, stream>>>(
        x, srw, srb, lng, lnb, XRhi, XRlo,
        Wq, Wk, Wv, Wp, Wqh, Wql, Wkh, Wkl, Wvh, Wvl, Wph);
    // 2) Q projection (768 blocks = exactly 3/CU)
    gemm_q<<<dim3(128, 6), 256, 0, stream>>>(x, Wqh, Wql, bq, Qhi, Qlo);
    // 3) fused K + V projections (BM=128, round-15 proven)
    gemm_kv<<<dim3(32, 6, 2), 256, 0, stream>>>(
        XRhi, XRlo, Wkh, Wkl, Wvh, Wvl, bk, bv, Khi, Vt);
    // 4) fused attention (v17: QK^T setprio removed)
    attn_mfma<<<dim3(32, 6, 4), 256, 0, stream>>>(Qhi, Qlo, Khi, Vt, Ob);
    // 5) output projection -> d_out (f32)
    gemm_out<<<dim3(128, 6), 256, 0, stream>>>(Ob, Wph, bp, out);
}

// Round 18
// 105.749 us; speedup vs baseline: 1.0946x; 1.0823x over previous
//
#include <hip/hip_runtime.h>
#include <hip/hip_bf16.h>
#include <math.h>

#define BB 4
#define NN 4096
#define CC 384
#define NHH 6
#define HDD 64
#define NKK 1024
#define LN_EPS 1e-5f

typedef _Float16 half8 __attribute__((ext_vector_type(8)));
typedef _Float16 half4v __attribute__((ext_vector_type(4)));
typedef _Float16 half2v __attribute__((ext_vector_type(2)));
typedef float f32x4 __attribute__((ext_vector_type(4)));

#define MFMA16(a, b, c) __builtin_amdgcn_mfma_f32_16x16x32_f16((a), (b), (c), 0, 0, 0)

#define GLL16(src, dst)                                                       \
    __builtin_amdgcn_global_load_lds(                                         \
        (const __attribute__((address_space(1))) void*)(src),                 \
        (__attribute__((address_space(3))) void*)(dst), 16, 0, 0)

// ---------------------------------------------------------------------------
// Q projection v18: A = x cast to f16 SINGLE on stage (x-rounding adds
// delta-logit ~2.2e-5, inside the sign-flip budget), W = pre-split pair,
// Y = (x @ Wq^T + bq) * 0.125 as f16 hi/lo pair (attention unchanged).
// 2 MFMAs per term (was 3); A staging cvt halved; AloS eliminated.
// ---------------------------------------------------------------------------
__global__ __launch_bounds__(256) void gemm_q(
    const float* __restrict__ x,
    const _Float16* __restrict__ Whi, const _Float16* __restrict__ Wlo,
    const float* __restrict__ bias,
    _Float16* __restrict__ Yhi, _Float16* __restrict__ Ylo)
{
    __shared__ _Float16 AhS[128 * 64];
    __shared__ _Float16 WhiS[64 * 64];
    __shared__ _Float16 WloS[64 * 64];

    const int tid = threadIdx.x;
    const int bm = blockIdx.x * 128;
    const int bn = blockIdx.y * 64;
    const int w = tid >> 6, lane = tid & 63;
    const int g = lane >> 4, n15 = lane & 15;

    f32x4 zero4 = {0.f, 0.f, 0.f, 0.f};
    f32x4 acc_hi[2][4], acc_lo[2][4];
#pragma unroll
    for (int mf = 0; mf < 2; ++mf)
#pragma unroll
        for (int nt = 0; nt < 4; ++nt) { acc_hi[mf][nt] = zero4; acc_lo[mf][nt] = zero4; }

    for (int k0 = 0; k0 < CC; k0 += 64) {
        __syncthreads();
        // ---- stage A: x -> f16 single (1 cvt/elem), swizzled b128 stores
#pragma unroll
        for (int i = 0; i < 4; ++i) {
            int id = tid + 256 * i;
            int row = id >> 3, dg = id & 7;
            const float* xp = x + (size_t)(bm + row) * CC + k0 + dg * 8;
            float4 a = *reinterpret_cast<const float4*>(xp);
            float4 b = *reinterpret_cast<const float4*>(xp + 4);
            half8 hv;
            hv[0] = (_Float16)a.x; hv[1] = (_Float16)a.y;
            hv[2] = (_Float16)a.z; hv[3] = (_Float16)a.w;
            hv[4] = (_Float16)b.x; hv[5] = (_Float16)b.y;
            hv[6] = (_Float16)b.z; hv[7] = (_Float16)b.w;
            int el = row * 64 + ((dg ^ (row & 7)) * 8);
            *reinterpret_cast<half8*>(&AhS[el]) = hv;
        }
#pragma unroll
        for (int i = 0; i < 2; ++i) {
            int id = tid + 256 * i;
            int row = id >> 3, dg = id & 7;
            size_t go = (size_t)(bn + row) * CC + k0 + dg * 8;
            half8 wh = *reinterpret_cast<const half8*>(Whi + go);
            half8 wl = *reinterpret_cast<const half8*>(Wlo + go);
            int el = row * 64 + ((dg ^ (row & 7)) * 8);
            *reinterpret_cast<half8*>(&WhiS[el]) = wh;
            *reinterpret_cast<half8*>(&WloS[el]) = wl;
        }
        __syncthreads();
#pragma unroll
        for (int kc = 0; kc < 2; ++kc) {
            const int blk = kc * 4 + g;
            half8 a_h[2], b_hi[4], b_lo[4];
#pragma unroll
            for (int mf = 0; mf < 2; ++mf) {
                int row = w * 32 + mf * 16 + n15;
                a_h[mf] = *reinterpret_cast<const half8*>(&AhS[row * 64 + ((blk ^ (row & 7)) * 8)]);
            }
#pragma unroll
            for (int nt = 0; nt < 4; ++nt) {
                int row = nt * 16 + n15;
                int el = row * 64 + ((blk ^ (row & 7)) * 8);
                b_hi[nt] = *reinterpret_cast<const half8*>(&WhiS[el]);
                b_lo[nt] = *reinterpret_cast<const half8*>(&WloS[el]);
            }
#pragma unroll
            for (int mf = 0; mf < 2; ++mf)
#pragma unroll
                for (int nt = 0; nt < 4; ++nt) {
                    acc_hi[mf][nt] = MFMA16(a_h[mf], b_hi[nt], acc_hi[mf][nt]);
                    acc_lo[mf][nt] = MFMA16(a_h[mf], b_lo[nt], acc_lo[mf][nt]);
                }
        }
    }
#pragma unroll
    for (int nt = 0; nt < 4; ++nt) {
        int col = bn + nt * 16 + n15;
        float bc = bias[col];
#pragma unroll
        for (int mf = 0; mf < 2; ++mf)
#pragma unroll
            for (int r = 0; r < 4; ++r) {
                size_t row = bm + w * 32 + mf * 16 + g * 4 + r;
                float y = (acc_hi[mf][nt][r] + acc_lo[mf][nt][r] * (1.0f / 256.0f) + bc) * 0.125f;
                _Float16 h = (_Float16)y;
                Yhi[row * CC + col] = h;
                Ylo[row * CC + col] = (_Float16)((y - (float)h) * 256.0f);
            }
    }
}

// ---------------------------------------------------------------------------
// Fused K-proj + V-proj (A = XR pre-split pair), BM=128 (round-15 proven).
// blockIdx.z: 0 -> K (f16 single), 1 -> V (transposed Vt[b][c][nk]).
// ---------------------------------------------------------------------------
__global__ __launch_bounds__(256) void gemm_kv(
    const _Float16* __restrict__ Ah, const _Float16* __restrict__ Al,
    const _Float16* __restrict__ Wkh, const _Float16* __restrict__ Wkl,
    const _Float16* __restrict__ Wvh, const _Float16* __restrict__ Wvl,
    const float* __restrict__ bk, const float* __restrict__ bv,
    _Float16* __restrict__ Khi, _Float16* __restrict__ Vt)
{
    __shared__ _Float16 AhiS[128 * 64];
    __shared__ _Float16 AloS[128 * 64];
    __shared__ _Float16 WhiS[64 * 64];
    __shared__ _Float16 WloS[64 * 64];

    const int tid = threadIdx.x;
    const int bm = blockIdx.x * 128;
    const int bn = blockIdx.y * 64;
    const int isV = blockIdx.z;
    const _Float16* Whi = isV ? Wvh : Wkh;
    const _Float16* Wlo = isV ? Wvl : Wkl;
    const float* bias = isV ? bv : bk;
    const int w = tid >> 6, lane = tid & 63;
    const int g = lane >> 4, n15 = lane & 15;

    f32x4 zero4 = {0.f, 0.f, 0.f, 0.f};
    f32x4 acc_hi[2][4], acc_lo[2][4];
#pragma unroll
    for (int mf = 0; mf < 2; ++mf)
#pragma unroll
        for (int nt = 0; nt < 4; ++nt) { acc_hi[mf][nt] = zero4; acc_lo[mf][nt] = zero4; }

    for (int k0 = 0; k0 < CC; k0 += 64) {
        __syncthreads();
#pragma unroll
        for (int i = 0; i < 4; ++i) {
            int id = tid + 256 * i;
            int row = id >> 3, dg = id & 7;
            size_t go = (size_t)(bm + row) * CC + k0 + dg * 8;
            half8 hv = *reinterpret_cast<const half8*>(Ah + go);
            half8 lv = *reinterpret_cast<const half8*>(Al + go);
            int el = row * 64 + ((dg ^ (row & 7)) * 8);
            *reinterpret_cast<half8*>(&AhiS[el]) = hv;
            *reinterpret_cast<half8*>(&AloS[el]) = lv;
        }
#pragma unroll
        for (int i = 0; i < 2; ++i) {
            int id = tid + 256 * i;
            int row = id >> 3, dg = id & 7;
            size_t go = (size_t)(bn + row) * CC + k0 + dg * 8;
            half8 wh = *reinterpret_cast<const half8*>(Whi + go);
            half8 wl = *reinterpret_cast<const half8*>(Wlo + go);
            int el = row * 64 + ((dg ^ (row & 7)) * 8);
            *reinterpret_cast<half8*>(&WhiS[el]) = wh;
            *reinterpret_cast<half8*>(&WloS[el]) = wl;
        }
        __syncthreads();
#pragma unroll
        for (int kc = 0; kc < 2; ++kc) {
            const int blk = kc * 4 + g;
            half8 a_hi[2], a_lo[2], b_hi[4], b_lo[4];
#pragma unroll
            for (int mf = 0; mf < 2; ++mf) {
                int row = w * 32 + mf * 16 + n15;
                int el = row * 64 + ((blk ^ (row & 7)) * 8);
                a_hi[mf] = *reinterpret_cast<const half8*>(&AhiS[el]);
                a_lo[mf] = *reinterpret_cast<const half8*>(&AloS[el]);
            }
#pragma unroll
            for (int nt = 0; nt < 4; ++nt) {
                int row = nt * 16 + n15;
                int el = row * 64 + ((blk ^ (row & 7)) * 8);
                b_hi[nt] = *reinterpret_cast<const half8*>(&WhiS[el]);
                b_lo[nt] = *reinterpret_cast<const half8*>(&WloS[el]);
            }
#pragma unroll
            for (int mf = 0; mf < 2; ++mf)
#pragma unroll
                for (int nt = 0; nt < 4; ++nt) {
                    acc_hi[mf][nt] = MFMA16(a_hi[mf], b_hi[nt], acc_hi[mf][nt]);
                    acc_lo[mf][nt] = MFMA16(a_hi[mf], b_lo[nt], acc_lo[mf][nt]);
                    acc_lo[mf][nt] = MFMA16(a_lo[mf], b_hi[nt], acc_lo[mf][nt]);
                }
        }
    }
#pragma unroll
    for (int nt = 0; nt < 4; ++nt) {
        int col = bn + nt * 16 + n15;
        float bc = bias[col];
#pragma unroll
        for (int mf = 0; mf < 2; ++mf)
#pragma unroll
            for (int r = 0; r < 4; ++r) {
                size_t row = bm + w * 32 + mf * 16 + g * 4 + r;
                float y = acc_hi[mf][nt][r] + acc_lo[mf][nt][r] * (1.0f / 256.0f) + bc;
                if (!isV) {
                    Khi[row * CC + col] = (_Float16)y;
                } else {
                    Vt[((row >> 10) * CC + col) * NKK + (row & 1023)] = (_Float16)y;
                }
            }
    }
}

// ---------------------------------------------------------------------------
// Out-projection GEMM (f16 A, f16 W, f32 out).
// ---------------------------------------------------------------------------
__global__ __launch_bounds__(256) void gemm_out(
    const _Float16* __restrict__ A, const _Float16* __restrict__ Whi,
    const float* __restrict__ bias, float* __restrict__ Yf)
{
    __shared__ _Float16 AhiS[128 * 64];
    __shared__ _Float16 WhiS[64 * 64];

    const int tid = threadIdx.x;
    const int bm = blockIdx.x * 128;
    const int bn = blockIdx.y * 64;
    const int w = tid >> 6, lane = tid & 63;
    const int g = lane >> 4, n15 = lane & 15;

    f32x4 zero4 = {0.f, 0.f, 0.f, 0.f};
    f32x4 acc[2][4];
#pragma unroll
    for (int mf = 0; mf < 2; ++mf)
#pragma unroll
        for (int nt = 0; nt < 4; ++nt) acc[mf][nt] = zero4;

    for (int k0 = 0; k0 < CC; k0 += 64) {
        __syncthreads();
#pragma unroll
        for (int i = 0; i < 4; ++i) {
            int id = tid + 256 * i;
            int row = id >> 3, dg = id & 7;
            half8 av = *reinterpret_cast<const half8*>(A + (size_t)(bm + row) * CC + k0 + dg * 8);
            int el = row * 64 + ((dg ^ (row & 7)) * 8);
            *reinterpret_cast<half8*>(&AhiS[el]) = av;
        }
#pragma unroll
        for (int i = 0; i < 2; ++i) {
            int id = tid + 256 * i;
            int row = id >> 3, dg = id & 7;
            half8 wh = *reinterpret_cast<const half8*>(Whi + (size_t)(bn + row) * CC + k0 + dg * 8);
            int el = row * 64 + ((dg ^ (row & 7)) * 8);
            *reinterpret_cast<half8*>(&WhiS[el]) = wh;
        }
        __syncthreads();
#pragma unroll
        for (int kc = 0; kc < 2; ++kc) {
            const int blk = kc * 4 + g;
            half8 a_hi[2], b_hi[4];
#pragma unroll
            for (int mf = 0; mf < 2; ++mf) {
                int row = w * 32 + mf * 16 + n15;
                a_hi[mf] = *reinterpret_cast<const half8*>(&AhiS[row * 64 + ((blk ^ (row & 7)) * 8)]);
            }
#pragma unroll
            for (int nt = 0; nt < 4; ++nt) {
                int row = nt * 16 + n15;
                b_hi[nt] = *reinterpret_cast<const half8*>(&WhiS[row * 64 + ((blk ^ (row & 7)) * 8)]);
            }
#pragma unroll
            for (int mf = 0; mf < 2; ++mf)
#pragma unroll
                for (int nt = 0; nt < 4; ++nt)
                    acc[mf][nt] = MFMA16(a_hi[mf], b_hi[nt], acc[mf][nt]);
        }
    }
#pragma unroll
    for (int nt = 0; nt < 4; ++nt) {
        int col = bn + nt * 16 + n15;
        float bc = bias[col];
#pragma unroll
        for (int mf = 0; mf < 2; ++mf)
#pragma unroll
            for (int r = 0; r < 4; ++r) {
                size_t row = bm + w * 32 + mf * 16 + g * 4 + r;
                Yf[row * CC + col] = acc[mf][nt][r] + bc;
            }
    }
}

// ---------------------------------------------------------------------------
// Fused: depthwise 2x2/2 conv + LayerNorm (blocks 0..4095) writing f16 pair,
// PLUS weight pre-split (blocks 4096..5247).
// ---------------------------------------------------------------------------
__global__ __launch_bounds__(128)
void srconv_splitw(const float* __restrict__ x, const float* __restrict__ srw,
                   const float* __restrict__ srb, const float* __restrict__ g,
                   const float* __restrict__ beta,
                   _Float16* __restrict__ xrh, _Float16* __restrict__ xrl,
                   const float* __restrict__ Wq, const float* __restrict__ Wk,
                   const float* __restrict__ Wv, const float* __restrict__ Wp,
                   _Float16* __restrict__ wqh, _Float16* __restrict__ wql,
                   _Float16* __restrict__ wkh, _Float16* __restrict__ wkl,
                   _Float16* __restrict__ wvh, _Float16* __restrict__ wvl,
                   _Float16* __restrict__ wph) {
    const int bid = blockIdx.x;
    const int tid = threadIdx.x;
    if (bid >= BB * NKK) {
        int i = (bid - BB * NKK) * 128 + tid;
        float q = Wq[i], k = Wk[i], v = Wv[i], p = Wp[i];
        _Float16 h;
        h = (_Float16)q; wqh[i] = h; wql[i] = (_Float16)((q - (float)h) * 256.0f);
        h = (_Float16)k; wkh[i] = h; wkl[i] = (_Float16)((k - (float)h) * 256.0f);
        h = (_Float16)v; wvh[i] = h; wvl[i] = (_Float16)((v - (float)h) * 256.0f);
        wph[i] = (_Float16)p;
        return;
    }
    const int row = bid;
    const int b  = row >> 10;
    const int nk = row & 1023;
    const int oy = nk >> 5;
    const int ox = nk & 31;
    const int n0 = (2 * oy) * 64 + 2 * ox;
    const float* xb = x + ((size_t)b * NN + n0) * CC;

    float vals[3];
    float lsum = 0.f, lsum2 = 0.f;
#pragma unroll
    for (int i = 0; i < 3; ++i) {
        const int c = tid + i * 128;
        const float4 w = *reinterpret_cast<const float4*>(srw + (size_t)c * 4);
        float v = xb[c] * w.x + xb[CC + c] * w.y +
                  xb[(size_t)64 * CC + c] * w.z + xb[(size_t)65 * CC + c] * w.w + srb[c];
        vals[i] = v;
        lsum += v;
        lsum2 += v * v;
    }
#pragma unroll
    for (int off = 32; off; off >>= 1) {
        lsum  += __shfl_down(lsum, off);
        lsum2 += __shfl_down(lsum2, off);
    }
    __shared__ float ssum[2], ssum2[2];
    if ((tid & 63) == 0) { ssum[tid >> 6] = lsum; ssum2[tid >> 6] = lsum2; }
    __syncthreads();
    const float tot  = ssum[0] + ssum[1];
    const float tot2 = ssum2[0] + ssum2[1];
    const float mu  = tot * (1.0f / 384.0f);
    const float var = tot2 * (1.0f / 384.0f) - mu * mu;
    const float rstd = 1.0f / sqrtf(var + LN_EPS);

    _Float16* oh = xrh + (size_t)row * CC;
    _Float16* ol = xrl + (size_t)row * CC;
#pragma unroll
    for (int i = 0; i < 3; ++i) {
        const int c = tid + i * 128;
        float v = (vals[i] - mu) * rstd * g[c] + beta[c];
        _Float16 h = (_Float16)v;
        oh[c] = h;
        ol[c] = (_Float16)((v - (float)h) * 256.0f);
    }
}

// ---------------------------------------------------------------------------
// Fused MFMA attention v17 (unchanged, best): f16 K, 2-MFMA QK^T, V hoisted
// to regs, triple-buffered, 1 barrier/kt, counted vmcnt, deferred l-reduce,
// setprio only on PV.
// ---------------------------------------------------------------------------
__global__ __launch_bounds__(256, 3)
void attn_mfma(const _Float16* __restrict__ Qhi, const _Float16* __restrict__ Qlo,
               const _Float16* __restrict__ Khi,
               const _Float16* __restrict__ Vt, _Float16* __restrict__ O)
{
    __shared__ _Float16 KhiS[3][32 * 64];   // [key][d]
    __shared__ _Float16 VTS[3][64 * 32];    // [d][key]
    __shared__ _Float16 PWS[4][1024];       // per-wave: 2 frags x [16 q][32 key]

    const int tid = threadIdx.x;
    const int w = tid >> 6, lane = tid & 63;
    const int g = lane >> 4, q15 = lane & 15;
    _Float16* PW = PWS[w];

    const int qt = blockIdx.x, h = blockIdx.y, b = blockIdx.z;

    half8 qh[2][2], ql[2][2];
    {
        size_t qoff = ((size_t)b * NN + qt * 128 + w * 32 + q15) * CC + h * 64 + g * 8;
#pragma unroll
        for (int f = 0; f < 2; ++f) {
            qh[f][0] = *reinterpret_cast<const half8*>(Qhi + qoff + f * 16 * CC);
            qh[f][1] = *reinterpret_cast<const half8*>(Qhi + qoff + f * 16 * CC + 32);
            ql[f][0] = *reinterpret_cast<const half8*>(Qlo + qoff + f * 16 * CC);
            ql[f][1] = *reinterpret_cast<const half8*>(Qlo + qoff + f * 16 * CC + 32);
        }
    }
    asm volatile("s_waitcnt vmcnt(0)" ::: "memory");

    const int krow = tid >> 3, kdg = tid & 7;
    const int kscol = (kdg ^ (krow & 7)) * 8;
    const _Float16* ksrc = Khi + ((size_t)b * NKK + krow) * CC + h * 64 + kscol;
    const int vd = tid >> 2, vkb = tid & 3;
    const _Float16* vsrc = Vt + ((size_t)b * CC + h * 64 + vd) * NKK + ((vkb ^ ((vd >> 1) & 3)) * 8);

    f32x4 zero4 = {0.f, 0.f, 0.f, 0.f};
    f32x4 o[2][4];
#pragma unroll
    for (int f = 0; f < 2; ++f)
#pragma unroll
        for (int nt = 0; nt < 4; ++nt) o[f][nt] = zero4;
    float l[2] = {0.f, 0.f};

#define ISSUE(kt, buf)                                                        \
    {                                                                         \
        GLL16(ksrc + (size_t)(kt) * 32 * CC, &KhiS[buf][tid * 8]);            \
        GLL16(vsrc + (kt) * 32,              &VTS[buf][tid * 8]);             \
    }

    auto COMPUTE = [&](const _Float16* KH, const _Float16* VT) {
        half8 vb[4];
#pragma unroll
        for (int nt = 0; nt < 4; ++nt) {
            int d = nt * 16 + q15;
            vb[nt] = *reinterpret_cast<const half8*>(&VT[d * 32 + ((g ^ ((d >> 1) & 3)) * 8)]);
        }
#pragma unroll
        for (int mt = 0; mt < 2; ++mt) {
            f32x4 sh[2], sl[2];
#pragma unroll
            for (int f = 0; f < 2; ++f) { sh[f] = zero4; sl[f] = zero4; }
#pragma unroll
            for (int kc = 0; kc < 2; ++kc) {
                int key = mt * 16 + q15;
                int el = key * 64 + (((kc * 4 + g) ^ (key & 7)) * 8);
                half8 ah = *reinterpret_cast<const half8*>(&KH[el]);
#pragma unroll
                for (int f = 0; f < 2; ++f) {
                    sh[f] = MFMA16(ah, qh[f][kc], sh[f]);
                    sl[f] = MFMA16(ah, ql[f][kc], sl[f]);
                }
            }
            int elw = q15 * 32 + (((mt * 2 + (g >> 1)) ^ ((q15 >> 1) & 3)) * 8) + (g & 1) * 4;
#pragma unroll
            for (int f = 0; f < 2; ++f) {
                half4v pk;
#pragma unroll
                for (int r = 0; r < 4; ++r) {
                    float sv = sh[f][r] + sl[f][r] * (1.0f / 256.0f);
                    float e = __expf(fabsf(sv));
                    l[f] += e;
                    pk[r] = (_Float16)__builtin_copysignf(e, sv);
                }
                *reinterpret_cast<half4v*>(&PW[elw + f * 512]) = pk;
            }
        }

        __builtin_amdgcn_s_setprio(1);
        {
            int pel = q15 * 32 + ((g ^ ((q15 >> 1) & 3)) * 8);
            half8 pa0 = *reinterpret_cast<const half8*>(&PW[pel]);
            half8 pa1 = *reinterpret_cast<const half8*>(&PW[pel + 512]);
#pragma unroll
            for (int nt = 0; nt < 4; ++nt) {
                o[0][nt] = MFMA16(pa0, vb[nt], o[0][nt]);
                o[1][nt] = MFMA16(pa1, vb[nt], o[1][nt]);
            }
        }
        __builtin_amdgcn_s_setprio(0);
    };

    ISSUE(0, 0);
    ISSUE(1, 1);

#pragma unroll 1
    for (int base = 0; base < 30; base += 3) {
        asm volatile("s_waitcnt vmcnt(2)" ::: "memory");
        __builtin_amdgcn_s_barrier();
        COMPUTE(KhiS[0], VTS[0]);
        ISSUE(base + 2, 2);

        asm volatile("s_waitcnt vmcnt(2)" ::: "memory");
        __builtin_amdgcn_s_barrier();
        COMPUTE(KhiS[1], VTS[1]);
        ISSUE(base + 3, 0);

        asm volatile("s_waitcnt vmcnt(2)" ::: "memory");
        __builtin_amdgcn_s_barrier();
        COMPUTE(KhiS[2], VTS[2]);
        if (base + 4 < 32) ISSUE(base + 4, 1);
    }
    asm volatile("s_waitcnt vmcnt(2)" ::: "memory");
    __builtin_amdgcn_s_barrier();
    COMPUTE(KhiS[0], VTS[0]);
    asm volatile("s_waitcnt vmcnt(0)" ::: "memory");
    __builtin_amdgcn_s_barrier();
    COMPUTE(KhiS[1], VTS[1]);
#undef ISSUE

#pragma unroll
    for (int f = 0; f < 2; ++f) {
        l[f] += __shfl_xor(l[f], 16);
        l[f] += __shfl_xor(l[f], 32);
    }
#pragma unroll
    for (int f = 0; f < 2; ++f) {
        float rl = 1.0f / l[f];
        float rlq[4];
#pragma unroll
        for (int r = 0; r < 4; ++r) rlq[r] = __shfl(rl, g * 4 + r);
#pragma unroll
        for (int nt = 0; nt < 4; ++nt)
#pragma unroll
            for (int r = 0; r < 4; ++r) {
                size_t row = (size_t)b * NN + qt * 128 + w * 32 + f * 16 + g * 4 + r;
                O[row * CC + h * 64 + nt * 16 + q15] = (_Float16)(o[f][nt][r] * rlq[r]);
            }
    }
}

// ---------------------------------------------------------------------------
extern "C" void kernel_launch(void* const* d_in, const int* in_sizes, int n_in,
                              void* d_out, int out_size, void* d_ws, size_t ws_size,
                              hipStream_t stream) {
    const float* x   = (const float*)d_in[0];
    const float* Wq  = (const float*)d_in[1];
    const float* bq  = (const float*)d_in[2];
    const float* Wk  = (const float*)d_in[3];
    const float* bk  = (const float*)d_in[4];
    const float* Wv  = (const float*)d_in[5];
    const float* bv  = (const float*)d_in[6];
    const float* srw = (const float*)d_in[7];
    const float* srb = (const float*)d_in[8];
    const float* lng = (const float*)d_in[9];
    const float* lnb = (const float*)d_in[10];
    const float* Wp  = (const float*)d_in[11];
    const float* bp  = (const float*)d_in[12];
    float* out = (float*)d_out;

    // workspace layout (~40 MB)
    char* wsb = (char*)d_ws;
    _Float16* Qhi  = (_Float16*)wsb;                   // 12.58 MB
    _Float16* Qlo  = (_Float16*)(wsb + 12582912);      // 12.58 MB (also attn O)
    _Float16* XRhi = (_Float16*)(wsb + 25165824);      // 3.15 MB
    _Float16* XRlo = (_Float16*)(wsb + 28311552);      // 3.15 MB
    _Float16* Khi  = (_Float16*)(wsb + 31457280);      // 3.15 MB
    _Float16* Vt   = (_Float16*)(wsb + 34603008);      // 3.15 MB [b][c][nk]
    _Float16* Wqh  = (_Float16*)(wsb + 37748736);      // 7 x 0.295 MB
    _Float16* Wql  = Wqh + 147456;
    _Float16* Wkh  = Wql + 147456;
    _Float16* Wkl  = Wkh + 147456;
    _Float16* Wvh  = Wkl + 147456;
    _Float16* Wvl  = Wvh + 147456;
    _Float16* Wph  = Wvl + 147456;
    _Float16* Ob   = Qlo;

    // 1) conv + LN -> pre-split pair, fused with weight pre-split
    srconv_splitw<<<dim3(BB * NKK + 1152), dim3(128), 0, stream>>>(
        x, srw, srb, lng, lnb, XRhi, XRlo,
        Wq, Wk, Wv, Wp, Wqh, Wql, Wkh, Wkl, Wvh, Wvl, Wph);
    // 2) Q projection (v18: f16-single x, 2-MFMA)
    gemm_q<<<dim3(128, 6), 256, 0, stream>>>(x, Wqh, Wql, bq, Qhi, Qlo);
    // 3) fused K + V projections (BM=128, round-15 proven)
    gemm_kv<<<dim3(32, 6, 2), 256, 0, stream>>>(
        XRhi, XRlo, Wkh, Wkl, Wvh, Wvl, bk, bv, Khi, Vt);
    // 4) fused attention (v17, unchanged)
    attn_mfma<<<dim3(32, 6, 4), 256, 0, stream>>>(Qhi, Qlo, Khi, Vt, Ob);
    // 5) output projection -> d_out (f32)
    gemm_out<<<dim3(128, 6), 256, 0, stream>>>(Ob, Wph, bp, out);
}